// Round 16
// baseline (146.553 us; speedup 1.0000x reference)
//
#include <hip/hip_runtime.h>
#include <hip/hip_bf16.h>

#define D 128
#define NPB 64
#define EPB1 2048          // edges per pass1/hist1 block
#define BDST 32            // dsts per fine bucket (bucket = dst >> 5)
#define CAP 1024           // max edges per bucket fast path (avg ~512)
#define MAXBINS 2048       // LDS cursor capacity (nb1 = ceil(n_dst/32) = 1563)
#define NCHUNK 8           // scan chunks along the block axis
#define NC 64              // src rows staged per p2agg chunk

typedef __attribute__((ext_vector_type(8))) short short8;   // 8 bf16 (4 VGPRs)
typedef __attribute__((ext_vector_type(4))) float f32x4;

static __device__ __forceinline__ unsigned short f32_to_bf16(float f) {
    unsigned int u = __float_as_uint(f);
    u = (u + 0x7FFFu + ((u >> 16) & 1u)) >> 16;   // RNE
    return (unsigned short)u;
}
static __device__ __forceinline__ float bf16lo(unsigned int r) {
    return __uint_as_float(r << 16);
}
static __device__ __forceinline__ float bf16hi(unsigned int r) {
    return __uint_as_float(r & 0xFFFF0000u);
}

// ---------------------------------------------------------------------------
// K0: convert w_embed rows into MFMA B-fragment layout (bf16), two sets.
// ---------------------------------------------------------------------------
__global__ void __launch_bounds__(256)
wconv_kernel(const float* __restrict__ w_embed, unsigned short* __restrict__ w_frag)
{
    int t = blockIdx.x * 256 + threadIdx.x;     // 4096 lane-frags total
    if (t >= 4096) return;
    int set  = t >> 11;
    int ks   = (t >> 9) & 3;
    int nt   = (t >> 6) & 7;
    int lane = t & 63;
    int wrow0 = set ? 130 : 0;
    int col   = nt * 16 + (lane & 15);
    int kbase = ks * 32 + (lane >> 4) * 8;
    unsigned short* dst = w_frag + (size_t)t * 8;
#pragma unroll
    for (int j = 0; j < 8; ++j)
        dst[j] = f32_to_bf16(w_embed[(size_t)(wrow0 + kbase + j) * D + col]);
}

// ---------------------------------------------------------------------------
// K1: fused MFMA node projection (src blocks then dst blocks in one grid).
// ---------------------------------------------------------------------------
__global__ void __launch_bounds__(256)
proj_both_kernel(const float* __restrict__ src_feat, const float* __restrict__ dst_feat,
                 const unsigned short* __restrict__ wfrag_base,
                 const float* __restrict__ w_att,
                 int n_src, int n_dst, int nblk_src,
                 unsigned short* __restrict__ srcp, unsigned short* __restrict__ dstp,
                 float* __restrict__ src_att, float* __restrict__ dst_att)
{
    const bool is_src = (blockIdx.x < nblk_src);
    const float* feats = is_src ? src_feat : dst_feat;
    const unsigned short* wfrag = is_src ? wfrag_base : wfrag_base + 16384;
    const int wrow = is_src ? 0 : 130;
    const int n_nodes = is_src ? n_src : n_dst;
    unsigned short* proj = is_src ? srcp : dstp;
    float* att = is_src ? src_att : dst_att;
    const int blk = is_src ? blockIdx.x : blockIdx.x - nblk_src;

    __shared__ unsigned short s_tile[NPB * D];   // 16 KB, swizzled
    __shared__ float s_red[NPB][4];

    const int tid = threadIdx.x;
    const int node0 = blk * NPB;

#pragma unroll
    for (int it = 0; it < 8; ++it) {
        int idx = it * 256 + tid;          // 2048 float4 groups
        int row = idx >> 5, c4 = idx & 31;
        int n = node0 + row;
        float4 v = (n < n_nodes)
                 ? *reinterpret_cast<const float4*>(&feats[(size_t)n * D + c4 * 4])
                 : make_float4(0.f, 0.f, 0.f, 0.f);
        unsigned short h[4];
        h[0] = f32_to_bf16(v.x); h[1] = f32_to_bf16(v.y);
        h[2] = f32_to_bf16(v.z); h[3] = f32_to_bf16(v.w);
        int byte = row * 256 + c4 * 8;
        byte ^= (row & 7) << 4;
        *reinterpret_cast<ushort4*>((char*)s_tile + byte) = *reinterpret_cast<ushort4*>(h);
    }
    __syncthreads();

    const int wv = tid >> 6, lane = tid & 63;

    f32x4 acc[8];
#pragma unroll
    for (int i = 0; i < 8; ++i) acc[i] = {0.f, 0.f, 0.f, 0.f};

    const int arow = wv * 16 + (lane & 15);
#pragma unroll
    for (int ks = 0; ks < 4; ++ks) {
        int abyte = arow * 256 + ks * 64 + (lane >> 4) * 16;
        abyte ^= (arow & 7) << 4;
        short8 a = *reinterpret_cast<const short8*>((char*)s_tile + abyte);
#pragma unroll
        for (int nt = 0; nt < 8; ++nt) {
            short8 b = *reinterpret_cast<const short8*>(wfrag + ((size_t)(ks * 8 + nt) * 64 + lane) * 8);
            acc[nt] = __builtin_amdgcn_mfma_f32_16x16x32_bf16(a, b, acc[nt], 0, 0, 0);
        }
    }

    // C/D: col = lane&15, row = (lane>>4)*4 + r
#pragma unroll
    for (int nt = 0; nt < 8; ++nt) {
#pragma unroll
        for (int r = 0; r < 4; ++r) {
            int node = node0 + wv * 16 + (lane >> 4) * 4 + r;
            if (node < n_nodes)
                proj[(size_t)node * D + nt * 16 + (lane & 15)] = f32_to_bf16(acc[nt][r]);
        }
    }

    // att scalar: 256 threads = 64 nodes x 4 k-quarters (reads swizzled LDS)
    const int na = tid & 63, kq = tid >> 6;
    float p = 0.f;
#pragma unroll
    for (int k = kq * 32; k < kq * 32 + 32; ++k) {
        int byte = (na * 256 + k * 2) ^ ((na & 7) << 4);
        unsigned short h = *reinterpret_cast<const unsigned short*>((char*)s_tile + byte);
        p += __uint_as_float(((unsigned int)h) << 16) * w_att[wrow + k];
    }
    s_red[na][kq] = p;
    __syncthreads();
    if (tid < NPB) {
        int n = node0 + tid;
        if (n < n_nodes)
            att[n] = s_red[tid][0] + s_red[tid][1] + s_red[tid][2] + s_red[tid][3];
    }
}

// ---------------------------------------------------------------------------
// K_h1: per-block bucket histogram (dst>>5), LDS-binned; bb block-major.
//     512 threads, 4 edges/thread via int4.
// ---------------------------------------------------------------------------
__global__ void __launch_bounds__(512)
hist1_kernel(const int* __restrict__ edst, int* __restrict__ bb,
             int n_edge, int nblk1, int nb1)
{
    __shared__ int bins[MAXBINS];
    const int tid = threadIdx.x, blk = blockIdx.x;
    for (int i = tid; i < nb1; i += 512) bins[i] = 0;
    __syncthreads();
    const int e0 = blk * EPB1 + tid * 4;
    if (e0 + 4 <= n_edge) {
        int4 d4 = *reinterpret_cast<const int4*>(&edst[e0]);
        atomicAdd(&bins[((unsigned)d4.x) >> 5], 1);
        atomicAdd(&bins[((unsigned)d4.y) >> 5], 1);
        atomicAdd(&bins[((unsigned)d4.z) >> 5], 1);
        atomicAdd(&bins[((unsigned)d4.w) >> 5], 1);
    } else {
        for (int e = e0; e < n_edge; ++e)
            atomicAdd(&bins[((unsigned)edst[e]) >> 5], 1);
    }
    __syncthreads();
    for (int i = tid; i < nb1; i += 512) bb[(size_t)blk * nb1 + i] = bins[i];
}

// ---------------------------------------------------------------------------
// K_cs1: chunk sums (read-only, coalesced across adjacent bins).
// ---------------------------------------------------------------------------
__global__ void __launch_bounds__(256)
chunksum_kernel(const int* __restrict__ bb, int* __restrict__ cs,
                int nb1, int nblk1, int cb)
{
    int t = blockIdx.x * 256 + threadIdx.x;
    if (t >= nb1 * NCHUNK) return;
    int c = t / nb1, bin = t - c * nb1;
    int b0 = c * cb, b1 = min(b0 + cb, nblk1);
    int s = 0;
    for (int blk = b0; blk < b1; ++blk)
        s += bb[(size_t)blk * nb1 + bin];
    cs[(size_t)c * nb1 + bin] = s;
}

// ---------------------------------------------------------------------------
// K_ms: midscan (single block): per-bin chunk scan + cross-bin scan.
// ---------------------------------------------------------------------------
__global__ void __launch_bounds__(1024)
midscan_kernel(int* __restrict__ cs, int* __restrict__ binstart,
               int nb1, int n_edge)
{
    __shared__ int s_tot[MAXBINS];
    __shared__ int s_w[16];
    __shared__ int s_total;
    __shared__ int s_carry;
    const int tid = threadIdx.x;
    const int lane = tid & 63, wid = tid >> 6;

    for (int bin = tid; bin < nb1; bin += 1024) {
        int run = 0;
#pragma unroll
        for (int c = 0; c < NCHUNK; ++c) {
            size_t idx = (size_t)c * nb1 + bin;
            int v = cs[idx];
            cs[idx] = run;
            run += v;
        }
        s_tot[bin] = run;
    }
    if (tid == 0) s_carry = 0;
    __syncthreads();

    for (int base = 0; base < nb1; base += 1024) {
        int idx = base + tid;
        int v = (idx < nb1) ? s_tot[idx] : 0;
        int x = v;
#pragma unroll
        for (int off = 1; off < 64; off <<= 1) {
            int y = __shfl_up(x, off);
            if (lane >= off) x += y;
        }
        if (lane == 63) s_w[wid] = x;
        __syncthreads();
        if (tid < 16) {
            int w = s_w[tid];
            int xi = w;
#pragma unroll
            for (int off = 1; off < 16; off <<= 1) {
                int y = __shfl_up(xi, off);
                if (tid >= off) xi += y;
            }
            if (tid == 15) s_total = xi;
            s_w[tid] = xi - w;   // exclusive wave offset
        }
        __syncthreads();
        if (idx < nb1) binstart[idx] = s_carry + s_w[wid] + (x - v);
        __syncthreads();
        if (tid == 0) s_carry += s_total;
        __syncthreads();
    }
    if (tid == 0) binstart[nb1] = n_edge;
}

// ---------------------------------------------------------------------------
// K_cw: chunk write-back, 8-deep batched (alias-broken).
// ---------------------------------------------------------------------------
__global__ void __launch_bounds__(256)
chunkwrite_kernel(int* __restrict__ bb, const int* __restrict__ cs,
                  int nb1, int nblk1, int cb)
{
    int t = blockIdx.x * 256 + threadIdx.x;
    if (t >= nb1 * NCHUNK) return;
    int c = t / nb1, bin = t - c * nb1;
    int b0 = c * cb, b1 = min(b0 + cb, nblk1);
    int carry = cs[(size_t)c * nb1 + bin];
    for (int blk0 = b0; blk0 < b1; blk0 += 8) {
        int v[8];
#pragma unroll
        for (int j = 0; j < 8; ++j) {
            int blk = blk0 + j;
            v[j] = (blk < b1) ? bb[(size_t)blk * nb1 + bin] : 0;
        }
#pragma unroll
        for (int j = 0; j < 8; ++j) {
            int blk = blk0 + j;
            if (blk < b1) bb[(size_t)blk * nb1 + bin] = carry;
            carry += v[j];
        }
    }
}

// ---------------------------------------------------------------------------
// K_p1: phase-split scatter. 512 threads, 4 edges/thread one-shot.
//     meta1 = {src | (dlow<<24), ew, d0, d1}, dlow = d&31.
// ---------------------------------------------------------------------------
__global__ void __launch_bounds__(512)
pass1_kernel(const int* __restrict__ esrc, const int* __restrict__ edst,
             const float* __restrict__ dist,
             const float* __restrict__ src_att, const float* __restrict__ dst_att,
             const float* __restrict__ w_att,
             const int* __restrict__ bb, const int* __restrict__ binstart,
             float4* __restrict__ meta1, int n_edge, int nblk1, int nb1)
{
    __shared__ int cur[MAXBINS];
    const int tid = threadIdx.x, blk = blockIdx.x;
    for (int i = tid; i < nb1; i += 512)
        cur[i] = binstart[i] + bb[(size_t)blk * nb1 + i];
    __syncthreads();

    const float wa0 = w_att[128], wa1 = w_att[129];
    const int e0 = blk * EPB1 + tid * 4;
    if (e0 + 4 <= n_edge) {
        int4 s4 = *reinterpret_cast<const int4*>(&esrc[e0]);
        int4 d4 = *reinterpret_cast<const int4*>(&edst[e0]);
        float4 da = *reinterpret_cast<const float4*>(&dist[2 * (size_t)e0]);
        float4 db = *reinterpret_cast<const float4*>(&dist[2 * (size_t)e0 + 4]);
        float sa0 = src_att[s4.x], sa1 = src_att[s4.y];
        float sa2 = src_att[s4.z], sa3 = src_att[s4.w];
        float ta0 = dst_att[d4.x], ta1 = dst_att[d4.y];
        float ta2 = dst_att[d4.z], ta3 = dst_att[d4.w];
        float c0 = sa0 + ta0 + da.x * wa0 + da.y * wa1;
        float c1 = sa1 + ta1 + da.z * wa0 + da.w * wa1;
        float c2 = sa2 + ta2 + db.x * wa0 + db.y * wa1;
        float c3 = sa3 + ta3 + db.z * wa0 + db.w * wa1;
        c0 = (c0 >= 0.f) ? c0 : 0.2f * c0;
        c1 = (c1 >= 0.f) ? c1 : 0.2f * c1;
        c2 = (c2 >= 0.f) ? c2 : 0.2f * c2;
        c3 = (c3 >= 0.f) ? c3 : 0.2f * c3;
        float w0 = __expf(c0), w1 = __expf(c1), w2 = __expf(c2), w3 = __expf(c3);
        int p0 = atomicAdd(&cur[((unsigned)d4.x) >> 5], 1);
        int p1 = atomicAdd(&cur[((unsigned)d4.y) >> 5], 1);
        int p2 = atomicAdd(&cur[((unsigned)d4.z) >> 5], 1);
        int p3 = atomicAdd(&cur[((unsigned)d4.w) >> 5], 1);
        meta1[p0] = make_float4(__int_as_float(s4.x | ((d4.x & 31) << 24)), w0, da.x, da.y);
        meta1[p1] = make_float4(__int_as_float(s4.y | ((d4.y & 31) << 24)), w1, da.z, da.w);
        meta1[p2] = make_float4(__int_as_float(s4.z | ((d4.z & 31) << 24)), w2, db.x, db.y);
        meta1[p3] = make_float4(__int_as_float(s4.w | ((d4.w & 31) << 24)), w3, db.z, db.w);
    } else {
        for (int e = e0; e < n_edge; ++e) {
            int s = esrc[e];
            int d = edst[e];
            float2 dd = *reinterpret_cast<const float2*>(&dist[2 * (size_t)e]);
            float sc = src_att[s] + dst_att[d] + dd.x * wa0 + dd.y * wa1;
            sc = (sc >= 0.f) ? sc : 0.2f * sc;
            float ew = __expf(sc);
            int pos = atomicAdd(&cur[((unsigned)d) >> 5], 1);
            meta1[pos] = make_float4(__int_as_float(s | ((d & 31) << 24)), ew, dd.x, dd.y);
        }
    }
}

// ---------------------------------------------------------------------------
// K_p2agg: fused fine-sort + LDS-staged aggregation.
//     One block per bucket of 32 dsts; 4 waves x 8 dsts.
//     Per 64-edge chunk: 256 threads cooperatively stage the needed srcp rows
//     into LDS (high MLP, coalesced), then waves accumulate from LDS.
// ---------------------------------------------------------------------------
__global__ void __launch_bounds__(256)
p2agg_kernel(const float4* __restrict__ meta1, const int* __restrict__ binstart,
             const unsigned short* __restrict__ srcp,   // bf16 [n_src,128]
             const unsigned short* __restrict__ dstp,   // bf16 [n_dst,128]
             const float* __restrict__ w_embed,
             float* __restrict__ out, int n_dst)
{
    __shared__ float4 s_meta[CAP];            // 16 KB, fine-sorted bucket meta
    __shared__ unsigned short s_rows[NC * D]; // 16 KB, staged src rows
    __shared__ int s_cnt[BDST];
    __shared__ int s_ofs[BDST + 1];
    __shared__ int s_cur[BDST];

    const int tid = threadIdx.x;
    const int b = blockIdx.x;
    const int bstart = binstart[b], bend = binstart[b + 1];
    const int bsize = bend - bstart;
    const int lane = tid & 63, wv = tid >> 6;   // 4 waves
    const int c0 = 2 * lane;

    const float2 wd0 = *reinterpret_cast<const float2*>(&w_embed[128 * D + c0]);
    const float2 wd1 = *reinterpret_cast<const float2*>(&w_embed[129 * D + c0]);

    if (tid < BDST) s_cnt[tid] = 0;
    __syncthreads();

    if (bsize <= CAP) {
        // pass A: fine counts (read only the packed word)
        for (int i = tid; i < bsize; i += 256) {
            int bits = __float_as_int(meta1[bstart + i].x);
            atomicAdd(&s_cnt[((unsigned)bits) >> 24], 1);
        }
        __syncthreads();
        // 32-bin exclusive scan (lanes 0..31 of wave 0)
        if (tid < BDST) {
            int v = s_cnt[tid];
            int x = v;
#pragma unroll
            for (int off = 1; off < BDST; off <<= 1) {
                int y = __shfl_up(x, off);
                if (tid >= off) x += y;
            }
            s_ofs[tid] = x - v;
            s_cur[tid] = x - v;
            if (tid == BDST - 1) s_ofs[BDST] = x;
        }
        __syncthreads();
        // pass B: scatter full records into sorted LDS positions
        for (int i = tid; i < bsize; i += 256) {
            float4 m = meta1[bstart + i];
            int dlow = ((unsigned)__float_as_int(m.x)) >> 24;
            int pos = atomicAdd(&s_cur[dlow], 1);
            s_meta[pos] = m;
        }
        __syncthreads();

        // per-dst bounds + sums pre-pass (lane-parallel + shfl reduce)
        int o0[8], o1[8];
        float sw[8], sd0[8], sd1[8];
#pragma unroll
        for (int k = 0; k < 8; ++k) {
            int dloc = k * 4 + wv;
            o0[k] = s_ofs[dloc];
            o1[k] = s_ofs[dloc + 1];
            float a = 0.f, p = 0.f, q = 0.f;
            for (int j = o0[k] + lane; j < o1[k]; j += 64) {
                float4 m = s_meta[j];
                a += m.y; p += m.y * m.z; q += m.y * m.w;
            }
#pragma unroll
            for (int off = 32; off > 0; off >>= 1) {
                a += __shfl_xor(a, off);
                p += __shfl_xor(p, off);
                q += __shfl_xor(q, off);
            }
            sw[k] = a; sd0[k] = p; sd1[k] = q;
        }

        float a0[8], a1[8];
#pragma unroll
        for (int k = 0; k < 8; ++k) { a0[k] = 0.f; a1[k] = 0.f; }

        // chunked: stage NC src rows -> accumulate from LDS
        for (int cb2 = 0; cb2 < bsize; cb2 += NC) {
            const int nrows = min(NC, bsize - cb2);
            __syncthreads();                    // protect s_rows from prior readers
            for (int i = tid; i < nrows * 16; i += 256) {
                int r = i >> 4, seg = i & 15;   // row, 16B segment
                int bits = __float_as_int(s_meta[cb2 + r].x);
                *reinterpret_cast<float4*>(&s_rows[r * D + seg * 8]) =
                    *reinterpret_cast<const float4*>(
                        &srcp[(size_t)(bits & 0xFFFFFF) * D + seg * 8]);
            }
            __syncthreads();
            const int ce = cb2 + nrows;
#pragma unroll
            for (int k = 0; k < 8; ++k) {
                int j0 = max(o0[k], cb2), j1 = min(o1[k], ce);
                for (int j = j0; j < j1; ++j) {
                    float at = s_meta[j].y;     // LDS broadcast
                    unsigned int r_ = *reinterpret_cast<const unsigned int*>(
                        &s_rows[(j - cb2) * D + c0]);
                    a0[k] += at * bf16lo(r_);
                    a1[k] += at * bf16hi(r_);
                }
            }
        }

        // epilogue: normalize + dist terms + dst_proj + relu
#pragma unroll
        for (int k = 0; k < 8; ++k) {
            int dloc = k * 4 + wv;
            int gd = b * BDST + dloc;
            if (gd >= n_dst) continue;
            float2* op = reinterpret_cast<float2*>(&out[(size_t)gd * D + c0]);
            if (o0[k] == o1[k]) { *op = make_float2(0.f, 0.f); continue; }
            float inv = 1.f / sw[k];
            unsigned int rd = *reinterpret_cast<const unsigned int*>(&dstp[(size_t)gd * D + c0]);
            float ov0 = (a0[k] + sd0[k] * wd0.x + sd1[k] * wd1.x) * inv + bf16lo(rd);
            float ov1 = (a1[k] + sd0[k] * wd0.y + sd1[k] * wd1.y) * inv + bf16hi(rd);
            *op = make_float2(fmaxf(ov0, 0.f), fmaxf(ov1, 0.f));
        }
    } else {
        // robust slow path (never taken at these sizes): chunked predicate scan
        float acc0[8], acc1[8], sw[8], s0[8], s1[8];
        for (int k = 0; k < 8; ++k) { acc0[k] = acc1[k] = sw[k] = s0[k] = s1[k] = 0.f; }
        for (int cs2 = bstart; cs2 < bend; cs2 += CAP) {
            int n = min(CAP, bend - cs2);
            __syncthreads();
            for (int i = tid; i < n; i += 256) s_meta[i] = meta1[cs2 + i];
            __syncthreads();
            for (int k = 0; k < 8; ++k) {
                int dloc = k * 4 + wv;
                for (int i = 0; i < n; ++i) {
                    float4 m = s_meta[i];
                    int bits = __float_as_int(m.x);
                    if ((int)(((unsigned)bits) >> 24) == dloc) {
                        unsigned int r = *reinterpret_cast<const unsigned int*>(
                            &srcp[(size_t)(bits & 0xFFFFFF) * D + c0]);
                        acc0[k] += m.y * bf16lo(r);
                        acc1[k] += m.y * bf16hi(r);
                        sw[k] += m.y;
                        s0[k] += m.y * m.z;
                        s1[k] += m.y * m.w;
                    }
                }
            }
        }
        for (int k = 0; k < 8; ++k) {
            int dloc = k * 4 + wv;
            int gd = b * BDST + dloc;
            if (gd >= n_dst) continue;
            float2* op = reinterpret_cast<float2*>(&out[(size_t)gd * D + c0]);
            if (sw[k] == 0.f) { *op = make_float2(0.f, 0.f); continue; }
            float inv = 1.f / sw[k];
            unsigned int rd = *reinterpret_cast<const unsigned int*>(&dstp[(size_t)gd * D + c0]);
            float ov0 = (acc0[k] + s0[k] * wd0.x + s1[k] * wd1.x) * inv + bf16lo(rd);
            float ov1 = (acc1[k] + s0[k] * wd0.y + s1[k] * wd1.y) * inv + bf16hi(rd);
            *op = make_float2(fmaxf(ov0, 0.f), fmaxf(ov1, 0.f));
        }
    }
}

// ---------------------------------------------------------------------------
extern "C" void kernel_launch(void* const* d_in, const int* in_sizes, int n_in,
                              void* d_out, int out_size, void* d_ws, size_t ws_size,
                              hipStream_t stream)
{
    const float* src_feat = (const float*)d_in[0];   // [N_SRC,128]
    const int*   esrc     = (const int*)d_in[1];     // [E]
    const float* dst_feat = (const float*)d_in[2];   // [N_DST,128]
    const int*   edst     = (const int*)d_in[3];     // [E]
    const float* dist     = (const float*)d_in[4];   // [E,2]
    const float* w_att    = (const float*)d_in[5];   // [258]
    const float* w_embed  = (const float*)d_in[6];   // [258,128]

    const int n_src  = in_sizes[0] / D;
    const int n_edge = in_sizes[1];
    const int n_dst  = in_sizes[2] / D;

    const int nb1   = (n_dst + BDST - 1) / BDST;     // buckets (1563)
    const int nblk1 = (n_edge + EPB1 - 1) / EPB1;    // pass-1 blocks (391)
    const int cb    = (nblk1 + NCHUNK - 1) / NCHUNK; // blocks per scan chunk (49)
    const size_t n1 = (size_t)nb1 * nblk1;

    // ---- workspace carve-up (256B-aligned) ----
    char* p = (char*)d_ws;
    auto carve = [&p](size_t bytes) {
        char* r = p;
        p += (bytes + 255) & ~size_t(255);
        return r;
    };
    unsigned short* src_projb = (unsigned short*)carve((size_t)n_src * D * 2);  // bf16
    unsigned short* dst_projb = (unsigned short*)carve((size_t)n_dst * D * 2);  // bf16
    float* src_att   = (float*)carve((size_t)n_src * 4);
    float* dst_att   = (float*)carve((size_t)n_dst * 4);
    int*   bb        = (int*)carve(n1 * 4);
    int*   cs        = (int*)carve((size_t)NCHUNK * nb1 * 4);
    int*   binstart  = (int*)carve((size_t)(nb1 + 1) * 4);
    unsigned short* w_frag = (unsigned short*)carve(2 * 4 * 8 * 64 * 8 * 2);  // 64 KB
    float4* meta1    = (float4*)carve((size_t)n_edge * 16);
    (void)ws_size;

    // K0: W -> bf16 fragment layout
    wconv_kernel<<<16, 256, 0, stream>>>(w_embed, w_frag);

    // K1: fused MFMA node projections
    const int nblk_src = (n_src + NPB - 1) / NPB;
    const int nblk_dst = (n_dst + NPB - 1) / NPB;
    proj_both_kernel<<<nblk_src + nblk_dst, 256, 0, stream>>>(
        src_feat, dst_feat, w_frag, w_att, n_src, n_dst, nblk_src,
        src_projb, dst_projb, src_att, dst_att);

    // K_h1: bucket histogram per pass1-block (block-major, coalesced)
    hist1_kernel<<<nblk1, 512, 0, stream>>>(edst, bb, n_edge, nblk1, nb1);

    // K_cs1 / K_ms / K_cw: parallel column scan of bb + binstart
    const int nthr_cs = nb1 * NCHUNK;
    chunksum_kernel<<<(nthr_cs + 255) / 256, 256, 0, stream>>>(bb, cs, nb1, nblk1, cb);
    midscan_kernel<<<1, 1024, 0, stream>>>(cs, binstart, nb1, n_edge);
    chunkwrite_kernel<<<(nthr_cs + 255) / 256, 256, 0, stream>>>(bb, cs, nb1, nblk1, cb);

    // K_p1: score/exp + bucket scatter (512 thr, phase-split ILP)
    pass1_kernel<<<nblk1, 512, 0, stream>>>(esrc, edst, dist, src_att, dst_att,
                                            w_att, bb, binstart, meta1,
                                            n_edge, nblk1, nb1);

    // K_p2agg: fused fine-sort + LDS-staged aggregation (256 thr)
    p2agg_kernel<<<nb1, 256, 0, stream>>>(meta1, binstart, src_projb, dst_projb,
                                          w_embed, (float*)d_out, n_dst);
}

// Round 17
// 112.703 us; speedup vs baseline: 1.3003x; 1.3003x over previous
//
#include <hip/hip_runtime.h>
#include <hip/hip_bf16.h>

#define D 128
#define NPB 64
#define EPB1 2048          // edges per pass1/hist1 block
#define BDST 32            // dsts per fine bucket (bucket = dst >> 5)
#define CAP 1024           // max edges per bucket fast path (avg ~512)
#define MAXBINS 2048       // LDS cursor capacity (nb1 = ceil(n_dst/32) = 1563)
#define NCHUNK 8           // scan chunks along the block axis

typedef __attribute__((ext_vector_type(8))) short short8;   // 8 bf16 (4 VGPRs)
typedef __attribute__((ext_vector_type(4))) float f32x4;

static __device__ __forceinline__ unsigned short f32_to_bf16(float f) {
    unsigned int u = __float_as_uint(f);
    u = (u + 0x7FFFu + ((u >> 16) & 1u)) >> 16;   // RNE
    return (unsigned short)u;
}
static __device__ __forceinline__ float bf16lo(unsigned int r) {
    return __uint_as_float(r << 16);
}
static __device__ __forceinline__ float bf16hi(unsigned int r) {
    return __uint_as_float(r & 0xFFFF0000u);
}

// ---------------------------------------------------------------------------
// K0: convert w_embed rows into MFMA B-fragment layout (bf16), two sets.
// ---------------------------------------------------------------------------
__global__ void __launch_bounds__(256)
wconv_kernel(const float* __restrict__ w_embed, unsigned short* __restrict__ w_frag)
{
    int t = blockIdx.x * 256 + threadIdx.x;     // 4096 lane-frags total
    if (t >= 4096) return;
    int set  = t >> 11;
    int ks   = (t >> 9) & 3;
    int nt   = (t >> 6) & 7;
    int lane = t & 63;
    int wrow0 = set ? 130 : 0;
    int col   = nt * 16 + (lane & 15);
    int kbase = ks * 32 + (lane >> 4) * 8;
    unsigned short* dst = w_frag + (size_t)t * 8;
#pragma unroll
    for (int j = 0; j < 8; ++j)
        dst[j] = f32_to_bf16(w_embed[(size_t)(wrow0 + kbase + j) * D + col]);
}

// ---------------------------------------------------------------------------
// K1: fused MFMA node projection (src blocks then dst blocks in one grid).
// ---------------------------------------------------------------------------
__global__ void __launch_bounds__(256)
proj_both_kernel(const float* __restrict__ src_feat, const float* __restrict__ dst_feat,
                 const unsigned short* __restrict__ wfrag_base,
                 const float* __restrict__ w_att,
                 int n_src, int n_dst, int nblk_src,
                 unsigned short* __restrict__ srcp, unsigned short* __restrict__ dstp,
                 float* __restrict__ src_att, float* __restrict__ dst_att)
{
    const bool is_src = (blockIdx.x < nblk_src);
    const float* feats = is_src ? src_feat : dst_feat;
    const unsigned short* wfrag = is_src ? wfrag_base : wfrag_base + 16384;
    const int wrow = is_src ? 0 : 130;
    const int n_nodes = is_src ? n_src : n_dst;
    unsigned short* proj = is_src ? srcp : dstp;
    float* att = is_src ? src_att : dst_att;
    const int blk = is_src ? blockIdx.x : blockIdx.x - nblk_src;

    __shared__ unsigned short s_tile[NPB * D];   // 16 KB, swizzled
    __shared__ float s_red[NPB][4];

    const int tid = threadIdx.x;
    const int node0 = blk * NPB;

#pragma unroll
    for (int it = 0; it < 8; ++it) {
        int idx = it * 256 + tid;          // 2048 float4 groups
        int row = idx >> 5, c4 = idx & 31;
        int n = node0 + row;
        float4 v = (n < n_nodes)
                 ? *reinterpret_cast<const float4*>(&feats[(size_t)n * D + c4 * 4])
                 : make_float4(0.f, 0.f, 0.f, 0.f);
        unsigned short h[4];
        h[0] = f32_to_bf16(v.x); h[1] = f32_to_bf16(v.y);
        h[2] = f32_to_bf16(v.z); h[3] = f32_to_bf16(v.w);
        int byte = row * 256 + c4 * 8;
        byte ^= (row & 7) << 4;
        *reinterpret_cast<ushort4*>((char*)s_tile + byte) = *reinterpret_cast<ushort4*>(h);
    }
    __syncthreads();

    const int wv = tid >> 6, lane = tid & 63;

    f32x4 acc[8];
#pragma unroll
    for (int i = 0; i < 8; ++i) acc[i] = {0.f, 0.f, 0.f, 0.f};

    const int arow = wv * 16 + (lane & 15);
#pragma unroll
    for (int ks = 0; ks < 4; ++ks) {
        int abyte = arow * 256 + ks * 64 + (lane >> 4) * 16;
        abyte ^= (arow & 7) << 4;
        short8 a = *reinterpret_cast<const short8*>((char*)s_tile + abyte);
#pragma unroll
        for (int nt = 0; nt < 8; ++nt) {
            short8 b = *reinterpret_cast<const short8*>(wfrag + ((size_t)(ks * 8 + nt) * 64 + lane) * 8);
            acc[nt] = __builtin_amdgcn_mfma_f32_16x16x32_bf16(a, b, acc[nt], 0, 0, 0);
        }
    }

    // C/D: col = lane&15, row = (lane>>4)*4 + r
#pragma unroll
    for (int nt = 0; nt < 8; ++nt) {
#pragma unroll
        for (int r = 0; r < 4; ++r) {
            int node = node0 + wv * 16 + (lane >> 4) * 4 + r;
            if (node < n_nodes)
                proj[(size_t)node * D + nt * 16 + (lane & 15)] = f32_to_bf16(acc[nt][r]);
        }
    }

    // att scalar: 256 threads = 64 nodes x 4 k-quarters (reads swizzled LDS)
    const int na = tid & 63, kq = tid >> 6;
    float p = 0.f;
#pragma unroll
    for (int k = kq * 32; k < kq * 32 + 32; ++k) {
        int byte = (na * 256 + k * 2) ^ ((na & 7) << 4);
        unsigned short h = *reinterpret_cast<const unsigned short*>((char*)s_tile + byte);
        p += __uint_as_float(((unsigned int)h) << 16) * w_att[wrow + k];
    }
    s_red[na][kq] = p;
    __syncthreads();
    if (tid < NPB) {
        int n = node0 + tid;
        if (n < n_nodes)
            att[n] = s_red[tid][0] + s_red[tid][1] + s_red[tid][2] + s_red[tid][3];
    }
}

// ---------------------------------------------------------------------------
// K_h1: per-block bucket histogram (dst>>5), LDS-binned; bb block-major.
// ---------------------------------------------------------------------------
__global__ void __launch_bounds__(512)
hist1_kernel(const int* __restrict__ edst, int* __restrict__ bb,
             int n_edge, int nblk1, int nb1)
{
    __shared__ int bins[MAXBINS];
    const int tid = threadIdx.x, blk = blockIdx.x;
    for (int i = tid; i < nb1; i += 512) bins[i] = 0;
    __syncthreads();
    const int e0 = blk * EPB1 + tid * 4;
    if (e0 + 4 <= n_edge) {
        int4 d4 = *reinterpret_cast<const int4*>(&edst[e0]);
        atomicAdd(&bins[((unsigned)d4.x) >> 5], 1);
        atomicAdd(&bins[((unsigned)d4.y) >> 5], 1);
        atomicAdd(&bins[((unsigned)d4.z) >> 5], 1);
        atomicAdd(&bins[((unsigned)d4.w) >> 5], 1);
    } else {
        for (int e = e0; e < n_edge; ++e)
            atomicAdd(&bins[((unsigned)edst[e]) >> 5], 1);
    }
    __syncthreads();
    for (int i = tid; i < nb1; i += 512) bb[(size_t)blk * nb1 + i] = bins[i];
}

// ---------------------------------------------------------------------------
// K_cs1: chunk sums (read-only, coalesced across adjacent bins).
// ---------------------------------------------------------------------------
__global__ void __launch_bounds__(256)
chunksum_kernel(const int* __restrict__ bb, int* __restrict__ cs,
                int nb1, int nblk1, int cb)
{
    int t = blockIdx.x * 256 + threadIdx.x;
    if (t >= nb1 * NCHUNK) return;
    int c = t / nb1, bin = t - c * nb1;
    int b0 = c * cb, b1 = min(b0 + cb, nblk1);
    int s = 0;
    for (int blk = b0; blk < b1; ++blk)
        s += bb[(size_t)blk * nb1 + bin];
    cs[(size_t)c * nb1 + bin] = s;
}

// ---------------------------------------------------------------------------
// K_ms: midscan (single block): per-bin chunk scan + cross-bin scan.
// ---------------------------------------------------------------------------
__global__ void __launch_bounds__(1024)
midscan_kernel(int* __restrict__ cs, int* __restrict__ binstart,
               int nb1, int n_edge)
{
    __shared__ int s_tot[MAXBINS];
    __shared__ int s_w[16];
    __shared__ int s_total;
    __shared__ int s_carry;
    const int tid = threadIdx.x;
    const int lane = tid & 63, wid = tid >> 6;

    for (int bin = tid; bin < nb1; bin += 1024) {
        int run = 0;
#pragma unroll
        for (int c = 0; c < NCHUNK; ++c) {
            size_t idx = (size_t)c * nb1 + bin;
            int v = cs[idx];
            cs[idx] = run;
            run += v;
        }
        s_tot[bin] = run;
    }
    if (tid == 0) s_carry = 0;
    __syncthreads();

    for (int base = 0; base < nb1; base += 1024) {
        int idx = base + tid;
        int v = (idx < nb1) ? s_tot[idx] : 0;
        int x = v;
#pragma unroll
        for (int off = 1; off < 64; off <<= 1) {
            int y = __shfl_up(x, off);
            if (lane >= off) x += y;
        }
        if (lane == 63) s_w[wid] = x;
        __syncthreads();
        if (tid < 16) {
            int w = s_w[tid];
            int xi = w;
#pragma unroll
            for (int off = 1; off < 16; off <<= 1) {
                int y = __shfl_up(xi, off);
                if (tid >= off) xi += y;
            }
            if (tid == 15) s_total = xi;
            s_w[tid] = xi - w;   // exclusive wave offset
        }
        __syncthreads();
        if (idx < nb1) binstart[idx] = s_carry + s_w[wid] + (x - v);
        __syncthreads();
        if (tid == 0) s_carry += s_total;
        __syncthreads();
    }
    if (tid == 0) binstart[nb1] = n_edge;
}

// ---------------------------------------------------------------------------
// K_cw: chunk write-back, 8-deep batched (alias-broken).
// ---------------------------------------------------------------------------
__global__ void __launch_bounds__(256)
chunkwrite_kernel(int* __restrict__ bb, const int* __restrict__ cs,
                  int nb1, int nblk1, int cb)
{
    int t = blockIdx.x * 256 + threadIdx.x;
    if (t >= nb1 * NCHUNK) return;
    int c = t / nb1, bin = t - c * nb1;
    int b0 = c * cb, b1 = min(b0 + cb, nblk1);
    int carry = cs[(size_t)c * nb1 + bin];
    for (int blk0 = b0; blk0 < b1; blk0 += 8) {
        int v[8];
#pragma unroll
        for (int j = 0; j < 8; ++j) {
            int blk = blk0 + j;
            v[j] = (blk < b1) ? bb[(size_t)blk * nb1 + bin] : 0;
        }
#pragma unroll
        for (int j = 0; j < 8; ++j) {
            int blk = blk0 + j;
            if (blk < b1) bb[(size_t)blk * nb1 + bin] = carry;
            carry += v[j];
        }
    }
}

// ---------------------------------------------------------------------------
// K_p1: phase-split scatter. 512 threads, 4 edges/thread one-shot.
//     meta1 = {src | (dlow<<24), ew, d0, d1}, dlow = d&31.
// ---------------------------------------------------------------------------
__global__ void __launch_bounds__(512)
pass1_kernel(const int* __restrict__ esrc, const int* __restrict__ edst,
             const float* __restrict__ dist,
             const float* __restrict__ src_att, const float* __restrict__ dst_att,
             const float* __restrict__ w_att,
             const int* __restrict__ bb, const int* __restrict__ binstart,
             float4* __restrict__ meta1, int n_edge, int nblk1, int nb1)
{
    __shared__ int cur[MAXBINS];
    const int tid = threadIdx.x, blk = blockIdx.x;
    for (int i = tid; i < nb1; i += 512)
        cur[i] = binstart[i] + bb[(size_t)blk * nb1 + i];
    __syncthreads();

    const float wa0 = w_att[128], wa1 = w_att[129];
    const int e0 = blk * EPB1 + tid * 4;
    if (e0 + 4 <= n_edge) {
        int4 s4 = *reinterpret_cast<const int4*>(&esrc[e0]);
        int4 d4 = *reinterpret_cast<const int4*>(&edst[e0]);
        float4 da = *reinterpret_cast<const float4*>(&dist[2 * (size_t)e0]);
        float4 db = *reinterpret_cast<const float4*>(&dist[2 * (size_t)e0 + 4]);
        float sa0 = src_att[s4.x], sa1 = src_att[s4.y];
        float sa2 = src_att[s4.z], sa3 = src_att[s4.w];
        float ta0 = dst_att[d4.x], ta1 = dst_att[d4.y];
        float ta2 = dst_att[d4.z], ta3 = dst_att[d4.w];
        float c0 = sa0 + ta0 + da.x * wa0 + da.y * wa1;
        float c1 = sa1 + ta1 + da.z * wa0 + da.w * wa1;
        float c2 = sa2 + ta2 + db.x * wa0 + db.y * wa1;
        float c3 = sa3 + ta3 + db.z * wa0 + db.w * wa1;
        c0 = (c0 >= 0.f) ? c0 : 0.2f * c0;
        c1 = (c1 >= 0.f) ? c1 : 0.2f * c1;
        c2 = (c2 >= 0.f) ? c2 : 0.2f * c2;
        c3 = (c3 >= 0.f) ? c3 : 0.2f * c3;
        float w0 = __expf(c0), w1 = __expf(c1), w2 = __expf(c2), w3 = __expf(c3);
        int p0 = atomicAdd(&cur[((unsigned)d4.x) >> 5], 1);
        int p1 = atomicAdd(&cur[((unsigned)d4.y) >> 5], 1);
        int p2 = atomicAdd(&cur[((unsigned)d4.z) >> 5], 1);
        int p3 = atomicAdd(&cur[((unsigned)d4.w) >> 5], 1);
        meta1[p0] = make_float4(__int_as_float(s4.x | ((d4.x & 31) << 24)), w0, da.x, da.y);
        meta1[p1] = make_float4(__int_as_float(s4.y | ((d4.y & 31) << 24)), w1, da.z, da.w);
        meta1[p2] = make_float4(__int_as_float(s4.z | ((d4.z & 31) << 24)), w2, db.x, db.y);
        meta1[p3] = make_float4(__int_as_float(s4.w | ((d4.w & 31) << 24)), w3, db.z, db.w);
    } else {
        for (int e = e0; e < n_edge; ++e) {
            int s = esrc[e];
            int d = edst[e];
            float2 dd = *reinterpret_cast<const float2*>(&dist[2 * (size_t)e]);
            float sc = src_att[s] + dst_att[d] + dd.x * wa0 + dd.y * wa1;
            sc = (sc >= 0.f) ? sc : 0.2f * sc;
            float ew = __expf(sc);
            int pos = atomicAdd(&cur[((unsigned)d) >> 5], 1);
            meta1[pos] = make_float4(__int_as_float(s | ((d & 31) << 24)), ew, dd.x, dd.y);
        }
    }
}

// ---------------------------------------------------------------------------
// K_p2agg: fused fine-sort + EDGE-PARALLEL aggregation.
//     One block per bucket of 32 dsts; 4 waves x 8 dsts (sequential per wave).
//     Wave layout per dst: 4 edges (eg = lane>>4) x 16 lanes (sg = lane&15),
//     each lane loads float4 (8 bf16 cols) of its edge's row. Fold edge
//     groups with shfl_xor(16,32); lanes 0..15 write the 512B output row.
// ---------------------------------------------------------------------------
__global__ void __launch_bounds__(256)
p2agg_kernel(const float4* __restrict__ meta1, const int* __restrict__ binstart,
             const unsigned short* __restrict__ srcp,   // bf16 [n_src,128]
             const unsigned short* __restrict__ dstp,   // bf16 [n_dst,128]
             const float* __restrict__ w_embed,
             float* __restrict__ out, int n_dst)
{
    __shared__ float4 s_meta[CAP];        // 16 KB, fine-sorted bucket meta
    __shared__ int s_cnt[BDST];
    __shared__ int s_ofs[BDST + 1];
    __shared__ int s_cur[BDST];

    const int tid = threadIdx.x;
    const int b = blockIdx.x;
    const int bstart = binstart[b], bend = binstart[b + 1];
    const int bsize = bend - bstart;
    const int lane = tid & 63, wv = tid >> 6;   // 4 waves
    const int eg = lane >> 4;                   // edge group 0..3
    const int sg = lane & 15;                   // 16B segment 0..15 (cols sg*8..+7)

    if (tid < BDST) s_cnt[tid] = 0;
    __syncthreads();

    if (bsize <= CAP) {
        // pass A: fine counts
        for (int i = tid; i < bsize; i += 256) {
            int bits = __float_as_int(meta1[bstart + i].x);
            atomicAdd(&s_cnt[((unsigned)bits) >> 24], 1);
        }
        __syncthreads();
        // 32-bin exclusive scan (lanes 0..31 of wave 0)
        if (tid < BDST) {
            int v = s_cnt[tid];
            int x = v;
#pragma unroll
            for (int off = 1; off < BDST; off <<= 1) {
                int y = __shfl_up(x, off);
                if (tid >= off) x += y;
            }
            s_ofs[tid] = x - v;
            s_cur[tid] = x - v;
            if (tid == BDST - 1) s_ofs[BDST] = x;
        }
        __syncthreads();
        // pass B: scatter full records into sorted LDS positions
        for (int i = tid; i < bsize; i += 256) {
            float4 m = meta1[bstart + i];
            int dlow = ((unsigned)__float_as_int(m.x)) >> 24;
            int pos = atomicAdd(&s_cur[dlow], 1);
            s_meta[pos] = m;
        }
        __syncthreads();

        // per-lane weight columns (fixed per sg), hoisted over all dsts
        const float4 wr0a = *reinterpret_cast<const float4*>(&w_embed[128 * D + sg * 8]);
        const float4 wr0b = *reinterpret_cast<const float4*>(&w_embed[128 * D + sg * 8 + 4]);
        const float4 wr1a = *reinterpret_cast<const float4*>(&w_embed[129 * D + sg * 8]);
        const float4 wr1b = *reinterpret_cast<const float4*>(&w_embed[129 * D + sg * 8 + 4]);

#pragma unroll
        for (int k = 0; k < 8; ++k) {
            const int dloc = k * 4 + wv;
            const int gd = b * BDST + dloc;
            if (gd >= n_dst) continue;
            const int o0 = s_ofs[dloc], o1 = s_ofs[dloc + 1];
            float* orow = &out[(size_t)gd * D];
            if (o0 == o1) {
                if (eg == 0) {
                    *reinterpret_cast<float4*>(&orow[sg * 8]) = make_float4(0.f, 0.f, 0.f, 0.f);
                    *reinterpret_cast<float4*>(&orow[sg * 8 + 4]) = make_float4(0.f, 0.f, 0.f, 0.f);
                }
                continue;
            }

            float a0 = 0.f, a1 = 0.f, a2 = 0.f, a3 = 0.f;
            float a4 = 0.f, a5 = 0.f, a6 = 0.f, a7 = 0.f;
            float psw = 0.f, psd0 = 0.f, psd1 = 0.f;

            for (int j0 = o0; j0 < o1; j0 += 4) {
                int j = j0 + eg;
                bool valid = (j < o1);
                float4 m = s_meta[valid ? j : o0];   // broadcast within eg group
                float at = valid ? m.y : 0.f;
                int src = __float_as_int(m.x) & 0xFFFFFF;
                float4 r = *reinterpret_cast<const float4*>(
                    &srcp[(size_t)src * D + sg * 8]);
                unsigned int r0 = __float_as_uint(r.x);
                unsigned int r1 = __float_as_uint(r.y);
                unsigned int r2 = __float_as_uint(r.z);
                unsigned int r3 = __float_as_uint(r.w);
                a0 += at * bf16lo(r0); a1 += at * bf16hi(r0);
                a2 += at * bf16lo(r1); a3 += at * bf16hi(r1);
                a4 += at * bf16lo(r2); a5 += at * bf16hi(r2);
                a6 += at * bf16lo(r3); a7 += at * bf16hi(r3);
                if (sg == 0) {
                    psw += at; psd0 += at * m.z; psd1 += at * m.w;
                }
            }

            // fold the 4 edge groups (classes preserve sg)
#pragma unroll
            for (int off = 16; off < 64; off <<= 1) {
                a0 += __shfl_xor(a0, off); a1 += __shfl_xor(a1, off);
                a2 += __shfl_xor(a2, off); a3 += __shfl_xor(a3, off);
                a4 += __shfl_xor(a4, off); a5 += __shfl_xor(a5, off);
                a6 += __shfl_xor(a6, off); a7 += __shfl_xor(a7, off);
                psw += __shfl_xor(psw, off);
                psd0 += __shfl_xor(psd0, off);
                psd1 += __shfl_xor(psd1, off);
            }
            const float sw  = __shfl(psw, 0);
            const float sd0 = __shfl(psd0, 0);
            const float sd1 = __shfl(psd1, 0);

            if (eg == 0) {   // lanes 0..15 hold folded sums for their 8 cols
                const float inv = 1.f / sw;
                unsigned int d0 = *reinterpret_cast<const unsigned int*>(&dstp[(size_t)gd * D + sg * 8]);
                unsigned int d1 = *reinterpret_cast<const unsigned int*>(&dstp[(size_t)gd * D + sg * 8 + 2]);
                unsigned int d2 = *reinterpret_cast<const unsigned int*>(&dstp[(size_t)gd * D + sg * 8 + 4]);
                unsigned int d3 = *reinterpret_cast<const unsigned int*>(&dstp[(size_t)gd * D + sg * 8 + 6]);
                float4 oA, oB;
                oA.x = fmaxf((a0 + sd0 * wr0a.x + sd1 * wr1a.x) * inv + bf16lo(d0), 0.f);
                oA.y = fmaxf((a1 + sd0 * wr0a.y + sd1 * wr1a.y) * inv + bf16hi(d0), 0.f);
                oA.z = fmaxf((a2 + sd0 * wr0a.z + sd1 * wr1a.z) * inv + bf16lo(d1), 0.f);
                oA.w = fmaxf((a3 + sd0 * wr0a.w + sd1 * wr1a.w) * inv + bf16hi(d1), 0.f);
                oB.x = fmaxf((a4 + sd0 * wr0b.x + sd1 * wr1b.x) * inv + bf16lo(d2), 0.f);
                oB.y = fmaxf((a5 + sd0 * wr0b.y + sd1 * wr1b.y) * inv + bf16hi(d2), 0.f);
                oB.z = fmaxf((a6 + sd0 * wr0b.z + sd1 * wr1b.z) * inv + bf16lo(d3), 0.f);
                oB.w = fmaxf((a7 + sd0 * wr0b.w + sd1 * wr1b.w) * inv + bf16hi(d3), 0.f);
                *reinterpret_cast<float4*>(&orow[sg * 8]) = oA;
                *reinterpret_cast<float4*>(&orow[sg * 8 + 4]) = oB;
            }
        }
    } else {
        // robust slow path (never taken at these sizes): chunked predicate scan
        const int c0 = 2 * lane;
        const float2 wd0 = *reinterpret_cast<const float2*>(&w_embed[128 * D + c0]);
        const float2 wd1 = *reinterpret_cast<const float2*>(&w_embed[129 * D + c0]);
        float acc0[8], acc1[8], sw[8], s0[8], s1[8];
        for (int k = 0; k < 8; ++k) { acc0[k] = acc1[k] = sw[k] = s0[k] = s1[k] = 0.f; }
        for (int cs2 = bstart; cs2 < bend; cs2 += CAP) {
            int n = min(CAP, bend - cs2);
            __syncthreads();
            for (int i = tid; i < n; i += 256) s_meta[i] = meta1[cs2 + i];
            __syncthreads();
            for (int k = 0; k < 8; ++k) {
                int dloc = k * 4 + wv;
                for (int i = 0; i < n; ++i) {
                    float4 m = s_meta[i];
                    int bits = __float_as_int(m.x);
                    if ((int)(((unsigned)bits) >> 24) == dloc) {
                        unsigned int r = *reinterpret_cast<const unsigned int*>(
                            &srcp[(size_t)(bits & 0xFFFFFF) * D + c0]);
                        acc0[k] += m.y * bf16lo(r);
                        acc1[k] += m.y * bf16hi(r);
                        sw[k] += m.y;
                        s0[k] += m.y * m.z;
                        s1[k] += m.y * m.w;
                    }
                }
            }
        }
        for (int k = 0; k < 8; ++k) {
            int dloc = k * 4 + wv;
            int gd = b * BDST + dloc;
            if (gd >= n_dst) continue;
            float2* op = reinterpret_cast<float2*>(&out[(size_t)gd * D + c0]);
            if (sw[k] == 0.f) { *op = make_float2(0.f, 0.f); continue; }
            float inv = 1.f / sw[k];
            unsigned int rd = *reinterpret_cast<const unsigned int*>(&dstp[(size_t)gd * D + c0]);
            float ov0 = (acc0[k] + s0[k] * wd0.x + s1[k] * wd1.x) * inv + bf16lo(rd);
            float ov1 = (acc1[k] + s0[k] * wd0.y + s1[k] * wd1.y) * inv + bf16hi(rd);
            *op = make_float2(fmaxf(ov0, 0.f), fmaxf(ov1, 0.f));
        }
    }
}

// ---------------------------------------------------------------------------
extern "C" void kernel_launch(void* const* d_in, const int* in_sizes, int n_in,
                              void* d_out, int out_size, void* d_ws, size_t ws_size,
                              hipStream_t stream)
{
    const float* src_feat = (const float*)d_in[0];   // [N_SRC,128]
    const int*   esrc     = (const int*)d_in[1];     // [E]
    const float* dst_feat = (const float*)d_in[2];   // [N_DST,128]
    const int*   edst     = (const int*)d_in[3];     // [E]
    const float* dist     = (const float*)d_in[4];   // [E,2]
    const float* w_att    = (const float*)d_in[5];   // [258]
    const float* w_embed  = (const float*)d_in[6];   // [258,128]

    const int n_src  = in_sizes[0] / D;
    const int n_edge = in_sizes[1];
    const int n_dst  = in_sizes[2] / D;

    const int nb1   = (n_dst + BDST - 1) / BDST;     // buckets (1563)
    const int nblk1 = (n_edge + EPB1 - 1) / EPB1;    // pass-1 blocks (391)
    const int cb    = (nblk1 + NCHUNK - 1) / NCHUNK; // blocks per scan chunk (49)
    const size_t n1 = (size_t)nb1 * nblk1;

    // ---- workspace carve-up (256B-aligned) ----
    char* p = (char*)d_ws;
    auto carve = [&p](size_t bytes) {
        char* r = p;
        p += (bytes + 255) & ~size_t(255);
        return r;
    };
    unsigned short* src_projb = (unsigned short*)carve((size_t)n_src * D * 2);  // bf16
    unsigned short* dst_projb = (unsigned short*)carve((size_t)n_dst * D * 2);  // bf16
    float* src_att   = (float*)carve((size_t)n_src * 4);
    float* dst_att   = (float*)carve((size_t)n_dst * 4);
    int*   bb        = (int*)carve(n1 * 4);
    int*   cs        = (int*)carve((size_t)NCHUNK * nb1 * 4);
    int*   binstart  = (int*)carve((size_t)(nb1 + 1) * 4);
    unsigned short* w_frag = (unsigned short*)carve(2 * 4 * 8 * 64 * 8 * 2);  // 64 KB
    float4* meta1    = (float4*)carve((size_t)n_edge * 16);
    (void)ws_size;

    // K0: W -> bf16 fragment layout
    wconv_kernel<<<16, 256, 0, stream>>>(w_embed, w_frag);

    // K1: fused MFMA node projections
    const int nblk_src = (n_src + NPB - 1) / NPB;
    const int nblk_dst = (n_dst + NPB - 1) / NPB;
    proj_both_kernel<<<nblk_src + nblk_dst, 256, 0, stream>>>(
        src_feat, dst_feat, w_frag, w_att, n_src, n_dst, nblk_src,
        src_projb, dst_projb, src_att, dst_att);

    // K_h1: bucket histogram per pass1-block (block-major, coalesced)
    hist1_kernel<<<nblk1, 512, 0, stream>>>(edst, bb, n_edge, nblk1, nb1);

    // K_cs1 / K_ms / K_cw: parallel column scan of bb + binstart
    const int nthr_cs = nb1 * NCHUNK;
    chunksum_kernel<<<(nthr_cs + 255) / 256, 256, 0, stream>>>(bb, cs, nb1, nblk1, cb);
    midscan_kernel<<<1, 1024, 0, stream>>>(cs, binstart, nb1, n_edge);
    chunkwrite_kernel<<<(nthr_cs + 255) / 256, 256, 0, stream>>>(bb, cs, nb1, nblk1, cb);

    // K_p1: score/exp + bucket scatter (512 thr, phase-split ILP)
    pass1_kernel<<<nblk1, 512, 0, stream>>>(esrc, edst, dist, src_att, dst_att,
                                            w_att, bb, binstart, meta1,
                                            n_edge, nblk1, nb1);

    // K_p2agg: fused fine-sort + edge-parallel aggregation (256 thr)
    p2agg_kernel<<<nb1, 256, 0, stream>>>(meta1, binstart, src_projb, dst_projb,
                                          w_embed, (float*)d_out, n_dst);
}